// Round 6
// baseline (702.581 us; speedup 1.0000x reference)
//
#include <hip/hip_runtime.h>

#define D 128
#define K 64
#define NROWS 200000
#define RT_ROWS 64
#define NTILES (NROWS / RT_ROWS)   // 3125
#define TPB 256
#define NBLK 512
#define TILE_BYTES 49152           // per-tile prep image: XH 16K | XL 16K | XT 16K
#define PSLOT2 8320                // K*D mean + K cluster_r, padded (floats)
#define NIT 11

typedef __attribute__((ext_vector_type(8))) short bf16x8;   // 8 bf16 = 4 VGPR
typedef __attribute__((ext_vector_type(4))) float f32x4;

// pass-kernel LDS arena (bytes)
#define XH  0          // x_hi [64][128] bf16, stride 256B, XOR-swizzled
#define XL  16384      // x_lo
#define XTO 32768      // x_hi transposed [128][64] bf16, stride 128B, swizzled
#define RTT 49152      // r^T [64 clusters][64 rows] bf16, swizzled
#define RSO 57344      // [4][64] f32 cluster_r wave partials
#define LDS_BYTES 58368

__device__ __forceinline__ int xrow_off(int row, int dim) {
  return (row * 256 + dim * 2) ^ ((row & 7) << 4);
}
__device__ __forceinline__ int xt_off(int dim, int row) {
  return (dim * 128 + row * 2) ^ ((dim & 7) << 4);
}
__device__ __forceinline__ int rt_off(int c, int row) {
  return (c * 128 + row * 2) ^ ((c & 7) << 4);
}
__device__ __forceinline__ ushort f2bf(float x) {   // round-to-nearest-even
  uint u = __float_as_uint(x);
  return (ushort)((u + 0x7FFF + ((u >> 16) & 1)) >> 16);
}
__device__ __forceinline__ float bf2f(ushort b) {
  return __uint_as_float(((uint)b) << 16);
}
__device__ __forceinline__ float dot4(const float4 a, const float4 b) {
  return a.x * b.x + a.y * b.y + a.z * b.z + a.w * b.w;
}
__device__ __forceinline__ void gload16(const char* g, char* l) {
  __builtin_amdgcn_global_load_lds(
      (__attribute__((address_space(1))) void*)(g),
      (__attribute__((address_space(3))) void*)(l), 16, 0, 0);
}

// ---------- prep (once): normalize X, bf16 hi/lo split, build pre-swizzled
// ---------- 48KB/tile LDS images (incl. transposed hi) in global scratch.
__global__ __launch_bounds__(TPB) void prep_kernel(
    const float* __restrict__ data, char* __restrict__ prep)
{
  __shared__ __align__(16) char smem[TILE_BYTES];
  const int t = threadIdx.x;
  const int tile = blockIdx.x;
  const int row = t >> 2, d0 = (t & 3) * 32;   // 4 threads per row

  const float4* src = (const float4*)(data + (size_t)(tile * RT_ROWS + row) * D + d0);
  float xf[32];
  float ss = 0.f;
#pragma unroll
  for (int i = 0; i < 8; ++i) {
    float4 v = src[i];
    ss += dot4(v, v);
    xf[4 * i] = v.x; xf[4 * i + 1] = v.y; xf[4 * i + 2] = v.z; xf[4 * i + 3] = v.w;
  }
  ss += __shfl_xor(ss, 1);
  ss += __shfl_xor(ss, 2);
  const float inv = 1.f / (sqrtf(ss) + 1e-6f);

  ushort hs[32], ls[32];
#pragma unroll
  for (int e = 0; e < 32; ++e) {
    const float a = xf[e] * inv;
    const ushort h = f2bf(a);
    hs[e] = h;
    ls[e] = f2bf(a - bf2f(h));
  }
#pragma unroll
  for (int j = 0; j < 4; ++j) {
    uint hp[4], lp[4];
#pragma unroll
    for (int q = 0; q < 4; ++q) {
      hp[q] = (uint)hs[8*j + 2*q] | ((uint)hs[8*j + 2*q + 1] << 16);
      lp[q] = (uint)ls[8*j + 2*q] | ((uint)ls[8*j + 2*q + 1] << 16);
    }
    *(uint4*)(smem + XH + xrow_off(row, d0 + 8*j)) = make_uint4(hp[0], hp[1], hp[2], hp[3]);
    *(uint4*)(smem + XL + xrow_off(row, d0 + 8*j)) = make_uint4(lp[0], lp[1], lp[2], lp[3]);
  }
#pragma unroll
  for (int e = 0; e < 32; ++e)
    *(ushort*)(smem + XTO + xt_off(d0 + e, row)) = hs[e];
  __syncthreads();
  // linear coalesced dump of the finished 48KB image
  char* gout = prep + (size_t)tile * TILE_BYTES;
#pragma unroll
  for (int i = 0; i < 12; ++i)
    *(uint4*)(gout + i * 4096 + t * 16) = *(const uint4*)(smem + i * 4096 + t * 16);
}

// ---------- per-iteration pass: stage via global_load_lds, dist MFMA (hi/lo
// ---------- split), softmax, r^T@X MFMA, atomic accumulate into acc_slot.
__global__ __launch_bounds__(TPB, 2) void pass_kernel(
    const char* __restrict__ prep, const float* __restrict__ mu_src,
    const int* __restrict__ temp_p, float* __restrict__ acc_slot,
    float* __restrict__ r_out, const int write_r)
{
  __shared__ __align__(16) char smem[LDS_BYTES];
  const int t = threadIdx.x;
  const int w = t >> 6, l = t & 63, lg = l >> 4, lr = l & 15;
  const float temp = (float)(*temp_p);

  // ---- prologue: normalize mu (scale-invariant: raw cluster_mean is fine),
  // ---- split to bf16 hi/lo in LDS, hoist all fragments to registers.
  {
    const int row = t >> 2, d0 = (t & 3) * 32;
    const float4* src = (const float4*)(mu_src + row * D + d0);
    float mf[32];
    float ss = 0.f;
#pragma unroll
    for (int i = 0; i < 8; ++i) {
      float4 v = src[i];
      ss += dot4(v, v);
      mf[4*i] = v.x; mf[4*i+1] = v.y; mf[4*i+2] = v.z; mf[4*i+3] = v.w;
    }
    ss += __shfl_xor(ss, 1);
    ss += __shfl_xor(ss, 2);
    const float inv = 1.f / (sqrtf(ss) + 1e-6f);
#pragma unroll
    for (int j = 0; j < 4; ++j) {
      uint hp[4], lp[4];
#pragma unroll
      for (int q = 0; q < 4; ++q) {
        const float a0 = mf[8*j + 2*q] * inv, a1 = mf[8*j + 2*q + 1] * inv;
        const ushort h0 = f2bf(a0), h1 = f2bf(a1);
        const ushort g0 = f2bf(a0 - bf2f(h0)), g1 = f2bf(a1 - bf2f(h1));
        hp[q] = (uint)h0 | ((uint)h1 << 16);
        lp[q] = (uint)g0 | ((uint)g1 << 16);
      }
      *(uint4*)(smem + XH + xrow_off(row, d0 + 8*j)) = make_uint4(hp[0], hp[1], hp[2], hp[3]);
      *(uint4*)(smem + XL + xrow_off(row, d0 + 8*j)) = make_uint4(lp[0], lp[1], lp[2], lp[3]);
    }
  }
  __syncthreads();
  bf16x8 muh[4][4], mul[4][4];
#pragma unroll
  for (int kc = 0; kc < 4; ++kc)
#pragma unroll
    for (int ns = 0; ns < 4; ++ns) {
      muh[kc][ns] = *(const bf16x8*)(smem + XH + xrow_off(16*ns + lr, kc*32 + lg*8));
      mul[kc][ns] = *(const bf16x8*)(smem + XL + xrow_off(16*ns + lr, kc*32 + lg*8));
    }
  __syncthreads();   // XH/XL now free for x tiles

  f32x4 accm[4][2];
#pragma unroll
  for (int ms = 0; ms < 4; ++ms)
#pragma unroll
    for (int n2 = 0; n2 < 2; ++n2) accm[ms][n2] = (f32x4){0.f, 0.f, 0.f, 0.f};
  float rsum[4] = {0.f, 0.f, 0.f, 0.f};

  for (int tile = blockIdx.x; tile < NTILES; tile += NBLK) {
    // ---- stage 48KB tile image direct to LDS (pre-swizzled source) ----
    const char* g = prep + (size_t)tile * TILE_BYTES + w * 1024 + l * 16;
#pragma unroll
    for (int i = 0; i < 12; ++i)
      gload16(g + i * 4096, smem + i * 4096 + w * 1024);
    __syncthreads();

    // ---- dist: rows 16w..16w+15, all 64 clusters; hi/lo split (3 MFMA) ----
    f32x4 pacc[4];
#pragma unroll
    for (int ns = 0; ns < 4; ++ns) pacc[ns] = (f32x4){0.f, 0.f, 0.f, 0.f};
#pragma unroll
    for (int kc = 0; kc < 4; ++kc) {
      const int doff = kc * 32 + lg * 8;
      const bf16x8 ah = *(const bf16x8*)(smem + XH + xrow_off(16*w + lr, doff));
      const bf16x8 al = *(const bf16x8*)(smem + XL + xrow_off(16*w + lr, doff));
#pragma unroll
      for (int ns = 0; ns < 4; ++ns) {
        pacc[ns] = __builtin_amdgcn_mfma_f32_16x16x32_bf16(ah, muh[kc][ns], pacc[ns], 0, 0, 0);
        pacc[ns] = __builtin_amdgcn_mfma_f32_16x16x32_bf16(al, muh[kc][ns], pacc[ns], 0, 0, 0);
        pacc[ns] = __builtin_amdgcn_mfma_f32_16x16x32_bf16(ah, mul[kc][ns], pacc[ns], 0, 0, 0);
      }
    }

    // ---- softmax over clusters (row = 16w + lg*4 + j; cluster = 16ns + lr)
    float rv[4][4], sinv[4];
#pragma unroll
    for (int j = 0; j < 4; ++j) {
      float sj = 0.f;
#pragma unroll
      for (int ns = 0; ns < 4; ++ns) { rv[ns][j] = __expf(temp * pacc[ns][j]); sj += rv[ns][j]; }
      sj += __shfl_xor(sj, 1); sj += __shfl_xor(sj, 2);
      sj += __shfl_xor(sj, 4); sj += __shfl_xor(sj, 8);
      sinv[j] = 1.f / sj;
    }
#pragma unroll
    for (int ns = 0; ns < 4; ++ns) {
      const float r0 = rv[ns][0]*sinv[0], r1 = rv[ns][1]*sinv[1],
                  r2 = rv[ns][2]*sinv[2], r3 = rv[ns][3]*sinv[3];
      const ushort h0 = f2bf(r0), h1 = f2bf(r1), h2 = f2bf(r2), h3 = f2bf(r3);
      rsum[ns] += (bf2f(h0) + bf2f(h1)) + (bf2f(h2) + bf2f(h3));
      *(uint2*)(smem + RTT + rt_off(16*ns + lr, 16*w + lg*4)) =
          make_uint2((uint)h0 | ((uint)h1 << 16), (uint)h2 | ((uint)h3 << 16));
      if (write_r) {
        const size_t rb = (size_t)tile * RT_ROWS + 16*w + lg*4;
        r_out[(rb + 0) * K + 16*ns + lr] = r0;
        r_out[(rb + 1) * K + 16*ns + lr] = r1;
        r_out[(rb + 2) * K + 16*ns + lr] = r2;
        r_out[(rb + 3) * K + 16*ns + lr] = r3;
      }
    }
    __syncthreads();

    // ---- accumulate cluster_mean += r^T @ Xn (wave w: dims 32w..32w+31) ----
#pragma unroll
    for (int kc2 = 0; kc2 < 2; ++kc2) {
      const int k0 = kc2 * 32 + lg * 8;
      bf16x8 af[4];
#pragma unroll
      for (int ms = 0; ms < 4; ++ms)
        af[ms] = *(const bf16x8*)(smem + RTT + rt_off(16*ms + lr, k0));
#pragma unroll
      for (int n2 = 0; n2 < 2; ++n2) {
        const int dim = 32*w + 16*n2 + lr;
        const bf16x8 bv = *(const bf16x8*)(smem + XTO + xt_off(dim, k0));
#pragma unroll
        for (int ms = 0; ms < 4; ++ms)
          accm[ms][n2] = __builtin_amdgcn_mfma_f32_16x16x32_bf16(af[ms], bv, accm[ms][n2], 0, 0, 0);
      }
    }
    __syncthreads();
  }

  // ---- epilogue: device-scope atomic accumulation (order-insensitive sums)
#pragma unroll
  for (int ms = 0; ms < 4; ++ms)
#pragma unroll
    for (int n2 = 0; n2 < 2; ++n2)
#pragma unroll
      for (int j = 0; j < 4; ++j)
        atomicAdd(&acc_slot[(16*ms + lg*4 + j) * D + 32*w + 16*n2 + lr], accm[ms][n2][j]);
#pragma unroll
  for (int ns = 0; ns < 4; ++ns) {
    rsum[ns] += __shfl_xor(rsum[ns], 16);
    rsum[ns] += __shfl_xor(rsum[ns], 32);
  }
  float* rs = (float*)(smem + RSO);
  if (lg == 0)
#pragma unroll
    for (int ns = 0; ns < 4; ++ns) rs[w * K + 16*ns + lr] = rsum[ns];
  __syncthreads();
  if (t < K)
    atomicAdd(&acc_slot[K*D + t], (rs[t] + rs[K + t]) + (rs[2*K + t] + rs[3*K + t]));
}

// final mu output: divide last slot's mean by cluster_r (only place / is needed)
__global__ __launch_bounds__(TPB) void final_kernel(
    const float* __restrict__ slot, float* __restrict__ mu_out)
{
  const int idx = blockIdx.x * TPB + threadIdx.x;   // 32 blocks x 256 = 8192
  mu_out[idx] = slot[idx] / slot[K * D + (idx >> 7)];
}

extern "C" void kernel_launch(void* const* d_in, const int* in_sizes, int n_in,
                              void* d_out, int out_size, void* d_ws, size_t ws_size,
                              hipStream_t stream)
{
  const float* data = (const float*)d_in[0];   // [200000,128] f32
  const float* init = (const float*)d_in[1];   // [64,128] f32
  const int* temp_p = (const int*)d_in[2];     // scalar 30
  float* out = (float*)d_out;                  // [0,8192) mu, then r [200000,64]

  char* prep = (char*)d_ws;                              // 153.6 MB of images
  float* slots = (float*)(prep + (size_t)NTILES * TILE_BYTES);  // 11 x 33.3 KB

  hipMemsetAsync(slots, 0, (size_t)NIT * PSLOT2 * sizeof(float), stream);
  prep_kernel<<<dim3(NTILES), dim3(TPB), 0, stream>>>(data, prep);

  // 10 iterations of _cluster#1 + 1 of _cluster#2 == 11 identical steps.
  // normalize(mean/r) == normalize(mean), so /cluster_r only at the end.
  for (int it = 0; it < NIT; ++it) {
    const float* mu_src = (it == 0) ? init : (slots + (size_t)(it - 1) * PSLOT2);
    pass_kernel<<<dim3(NBLK), dim3(TPB), 0, stream>>>(
        prep, mu_src, temp_p, slots + (size_t)it * PSLOT2, out + K*D, it == NIT - 1);
  }
  final_kernel<<<dim3(32), dim3(TPB), 0, stream>>>(
      slots + (size_t)(NIT - 1) * PSLOT2, out);
}